// Round 2
// baseline (536.864 us; speedup 1.0000x reference)
//
#include <hip/hip_runtime.h>

typedef unsigned short u16;
typedef unsigned int u32;
typedef __attribute__((ext_vector_type(8))) __bf16 bf16x8;
typedef __attribute__((ext_vector_type(4))) float floatx4;
typedef const __attribute__((address_space(1))) unsigned char glob_u8;
typedef __attribute__((address_space(3))) unsigned char lds_u8;

#define DEV __device__ __forceinline__
#define NB 512u

DEV u16 f2bf(float f) {
  u32 u = __builtin_bit_cast(u32, f);
  u = (u + 0x7fffu + ((u >> 16) & 1u)) >> 16;
  return (u16)u;
}
DEV float bf2f(u16 h) {
  u32 u = ((u32)h) << 16;
  return __builtin_bit_cast(float, u);
}
DEV floatx4 MFMA(bf16x8 a, bf16x8 b, floatx4 c) {
  return __builtin_amdgcn_mfma_f32_16x16x32_bf16(a, b, c, 0, 0, 0);
}

// Software grid barrier (sense via generation counter). All 512 blocks are
// co-resident (74.75KB LDS -> 2 blocks/CU hard cap, grid = 2*256 exactly).
// Bounded spin: on residency violation we break (-> wrong answer) not hang.
DEV void grid_sync(unsigned* cnt, unsigned* gen) {
  __syncthreads();
  if (threadIdx.x == 0) {
    __threadfence();
    unsigned g = __hip_atomic_load(gen, __ATOMIC_RELAXED, __HIP_MEMORY_SCOPE_AGENT);
    unsigned a = __hip_atomic_fetch_add(cnt, 1u, __ATOMIC_ACQ_REL, __HIP_MEMORY_SCOPE_AGENT);
    if (a == NB - 1u) {
      __hip_atomic_store(cnt, 0u, __ATOMIC_RELAXED, __HIP_MEMORY_SCOPE_AGENT);
      __hip_atomic_store(gen, g + 1u, __ATOMIC_RELEASE, __HIP_MEMORY_SCOPE_AGENT);
    } else {
      int guard = 0;
      while (__hip_atomic_load(gen, __ATOMIC_ACQUIRE, __HIP_MEMORY_SCOPE_AGENT) == g) {
        __builtin_amdgcn_s_sleep(4);
        if (++guard > (1 << 22)) break;
      }
    }
    __threadfence();
  }
  __syncthreads();
}

// LDS layout (bytes), aliased per stage:
//  stage1: As1[128*40]u16 @0 (10240) | Bs1[64*40]u16 @10240 (5120)
//  stage2: Kt[2][4096]u16 @0 | Vt[2][4096]u16 @16384 | Bt[2][4096]f32 @32768
//          | Ps[4*16*72]u16 @65536        total 74752
//  stage3: As3[32*40]u16 @0 | Bs3[64*40]u16 @2560
__global__ __launch_bounds__(256, 2) void fused_pipeline_k(
    const float* __restrict__ x, const float* __restrict__ bias,
    const float* __restrict__ Wq, const float* __restrict__ Wkv,
    const float* __restrict__ Wo, const float* __restrict__ bo,
    const float* __restrict__ Wg, const float* __restrict__ bg,
    u16* __restrict__ xb, u16* __restrict__ WcatT, u16* __restrict__ WoT,
    u16* __restrict__ qb, u16* __restrict__ kfrag, u16* __restrict__ vfrag,
    u16* __restrict__ gb, u16* __restrict__ ogb, float* __restrict__ out,
    unsigned* bar) {
  __shared__ __attribute__((aligned(16))) unsigned char SM[74752];
  const int tid = threadIdx.x;
  const int bid = blockIdx.x;
  const int wave = tid >> 6, lane = tid & 63;
  const int lane15 = lane & 15, quad = lane >> 4;

  // ---------------- stage 0: convert x / weights -> bf16 ----------------
  {
    const int i0 = bid * 256 + tid;
#pragma unroll 1
    for (int it = 0; it < 13; ++it) {
      int i = i0 + it * 131072;
      if (i < 1048576) { xb[i] = f2bf(x[i]); continue; }
      int j = i - 1048576;
      if (j < 524288) {
        int n = j >> 8, kk = j & 255;
        float v;
        if (n < 512) v = Wq[kk * 512 + n];
        else if (n < 1536) v = Wkv[kk * 1024 + (n - 512)];
        else v = Wg[kk * 512 + (n - 1536)];
        WcatT[j] = f2bf(v);
        continue;
      }
      j -= 524288;
      int n = j >> 9, kk = j & 511;
      WoT[j] = f2bf(Wo[kk * 256 + n]);
    }
  }
  grid_sync(bar, bar + 32);

  // ---------------- stage 1: QKVG gemm, 2 (128x64) tiles/block ----------------
  {
    u16* As = (u16*)SM;
    u16* Bs = (u16*)(SM + 10240);
    const int wm = (wave & 1) * 64, wn = (wave >> 1) * 32;
    const int rowA = tid >> 1, segA = (tid & 1) * 16;
    const int rowB = tid >> 2, segB = (tid & 3) * 8;
#pragma unroll 1
    for (int it = 0; it < 2; ++it) {
      const int t = bid * 2 + it;
      const int rm0 = (t & 31) * 128;
      const int cn0 = (t >> 5) * 64;
      floatx4 acc[4][2] = {};
      uint4 a0 = *(const uint4*)(xb + (rm0 + rowA) * 256 + segA);
      uint4 a1 = *(const uint4*)(xb + (rm0 + rowA) * 256 + segA + 8);
      uint4 b0 = *(const uint4*)(WcatT + (cn0 + rowB) * 256 + segB);
#pragma unroll 1
      for (int k0 = 0; k0 < 256; k0 += 32) {
        __syncthreads();
        *(uint4*)(As + rowA * 40 + segA) = a0;
        *(uint4*)(As + rowA * 40 + segA + 8) = a1;
        *(uint4*)(Bs + rowB * 40 + segB) = b0;
        __syncthreads();
        if (k0 < 224) {
          a0 = *(const uint4*)(xb + (rm0 + rowA) * 256 + k0 + 32 + segA);
          a1 = *(const uint4*)(xb + (rm0 + rowA) * 256 + k0 + 32 + segA + 8);
          b0 = *(const uint4*)(WcatT + (cn0 + rowB) * 256 + k0 + 32 + segB);
        }
        bf16x8 af[4], bfr[2];
#pragma unroll
        for (int mt = 0; mt < 4; ++mt) af[mt] = *(const bf16x8*)(As + (wm + mt * 16 + lane15) * 40 + quad * 8);
#pragma unroll
        for (int nt = 0; nt < 2; ++nt) bfr[nt] = *(const bf16x8*)(Bs + (wn + nt * 16 + lane15) * 40 + quad * 8);
#pragma unroll
        for (int mt = 0; mt < 4; ++mt)
#pragma unroll
          for (int nt = 0; nt < 2; ++nt)
            acc[mt][nt] = MFMA(af[mt], bfr[nt], acc[mt][nt]);
      }
#pragma unroll
      for (int mt = 0; mt < 4; ++mt)
#pragma unroll
        for (int nt = 0; nt < 2; ++nt)
#pragma unroll
          for (int r = 0; r < 4; ++r) {
            int row = rm0 + wm + mt * 16 + quad * 4 + r;
            int col = cn0 + wn + nt * 16 + lane15;
            float v = acc[mt][nt][r];
            int b = row >> 10, n = row & 1023;
            if (col < 512) {
              int h = col >> 6, d = col & 63;
              qb[((b * 8 + h) * 1024 + n) * 64 + d] = f2bf(v * 0.125f);
            } else if (col < 1024) {
              int c = col - 512, h = c >> 6, d = c & 63;
              int bh2 = b * 8 + h;
              int tt = n >> 4, l15 = n & 15;
              int half = d >> 5, qd = (d >> 3) & 3, e = d & 7;
              kfrag[(size_t)bh2 * 65536 + tt * 1024 + half * 512 + (qd * 16 + l15) * 8 + e] = f2bf(v);
            } else if (col < 1536) {
              int c = col - 1024, h = c >> 6, d = c & 63;
              int bh2 = b * 8 + h;
              int t64 = n >> 6, ck = (n >> 5) & 1, qd = (n >> 3) & 3, e = n & 7;
              int dt = d >> 4, l15 = d & 15;
              vfrag[(size_t)bh2 * 65536 + t64 * 4096 + dt * 1024 + ck * 512 + (qd * 16 + l15) * 8 + e] = f2bf(v);
            } else {
              int c = col - 1536;
              float g = 1.0f / (1.0f + __expf(-(v + bg[c])));
              gb[row * 512 + c] = f2bf(g);
            }
          }
    }
  }
  grid_sync(bar, bar + 32);

  // ---------------- stage 2: fused attention (full 1024 keys) ----------------
  // bh = bid&31 keeps all 16 q0-blocks of a head on one XCD (ids differ by 32
  // == 0 mod 8) -> K/V re-reads are XCD-L2-local.
  {
    u16* KtL = (u16*)SM;                  // [2][4096]
    u16* VtL = (u16*)(SM + 16384);        // [2][4096]
    float* BtL = (float*)(SM + 32768);    // [2][4096]
    u16* PsL = (u16*)(SM + 65536);        // [4*16*72]
    const int bh = bid & 31;
    const int q0 = (bid >> 5) * 64;

    bf16x8 qf0, qf1;
    {
      const u16* qrow = qb + ((size_t)(bh * 1024 + q0 + wave * 16 + lane15)) * 64 + quad * 8;
      qf0 = *(const bf16x8*)(qrow);
      qf1 = *(const bf16x8*)(qrow + 32);
    }
    bf16x8 ones;
#pragma unroll
    for (int e = 0; e < 8; ++e) ones[e] = __builtin_bit_cast(__bf16, (u16)0x3F80);

    floatx4 oacc[4] = {};
    floatx4 lacc = {};

    u16* Pw = PsL + wave * (16 * 72);
    const u16* kp = kfrag + (size_t)bh * 65536;
    const u16* vp = vfrag + (size_t)bh * 65536;

    auto stage = [&](int kt, int bufi) {
      const int kb0 = kt * 64;
      const u16* kS = kp + kb0 * 64;
      const u16* vS = vp + kb0 * 64;
#pragma unroll
      for (int c = 0; c < 2; ++c) {
        int ch = wave * 2 + c;
        __builtin_amdgcn_global_load_lds((glob_u8*)(kS + ch * 512 + lane * 8),
                                         (lds_u8*)(KtL + bufi * 4096 + ch * 512), 16, 0, 0);
        __builtin_amdgcn_global_load_lds((glob_u8*)(vS + ch * 512 + lane * 8),
                                         (lds_u8*)(VtL + bufi * 4096 + ch * 512), 16, 0, 0);
      }
#pragma unroll
      for (int c = 0; c < 4; ++c) {
        int ch = wave * 4 + c;
        const float* bS = bias + ((size_t)(bh * 1024 + q0 + ch * 4 + quad)) * 1024 + kb0 + lane15 * 4;
        __builtin_amdgcn_global_load_lds((glob_u8*)bS, (lds_u8*)(BtL + bufi * 4096 + ch * 256), 16, 0, 0);
      }
    };

    stage(0, 0);
    __syncthreads();
    int cur = 0;
#pragma unroll 1
    for (int kt = 0; kt < 16; ++kt) {
      if (kt < 15) stage(kt + 1, cur ^ 1);
      const u16* Ktc = KtL + cur * 4096;
      const u16* Vtc = VtL + cur * 4096;
      const float* Btc = BtL + cur * 4096;
      floatx4 s[4];
#pragma unroll
      for (int j = 0; j < 4; ++j) {
        bf16x8 kf0 = *(const bf16x8*)(Ktc + j * 1024 + lane * 8);
        bf16x8 kf1 = *(const bf16x8*)(Ktc + j * 1024 + 512 + lane * 8);
        floatx4 z = {};
        z = MFMA(qf0, kf0, z);
        s[j] = MFMA(qf1, kf1, z);
      }
#pragma unroll
      for (int j = 0; j < 4; ++j)
#pragma unroll
        for (int r = 0; r < 4; ++r)
          s[j][r] = __expf(s[j][r] + Btc[(wave * 16 + quad * 4 + r) * 64 + j * 16 + lane15] - 8.0f);
#pragma unroll
      for (int j = 0; j < 4; ++j)
#pragma unroll
        for (int r = 0; r < 4; ++r)
          Pw[(quad * 4 + r) * 72 + j * 16 + lane15] = f2bf(s[j][r]);
      bf16x8 pf0 = *(const bf16x8*)(Pw + lane15 * 72 + quad * 8);
      bf16x8 pf1 = *(const bf16x8*)(Pw + lane15 * 72 + 32 + quad * 8);

      lacc = MFMA(pf0, ones, lacc);
      lacc = MFMA(pf1, ones, lacc);
#pragma unroll
      for (int dt = 0; dt < 4; ++dt) {
        bf16x8 vf0 = *(const bf16x8*)(Vtc + dt * 1024 + lane * 8);
        bf16x8 vf1 = *(const bf16x8*)(Vtc + dt * 1024 + 512 + lane * 8);
        oacc[dt] = MFMA(pf0, vf0, oacc[dt]);
        oacc[dt] = MFMA(pf1, vf1, oacc[dt]);
      }
      __syncthreads();
      cur ^= 1;
    }

    const int b = bh >> 3, h = bh & 7;
#pragma unroll
    for (int r = 0; r < 4; ++r) {
      int q = q0 + wave * 16 + quad * 4 + r;
      float inv = 1.0f / lacc[r];
      size_t base = ((size_t)(b * 1024 + q)) * 512 + h * 64;
#pragma unroll
      for (int dt = 0; dt < 4; ++dt) {
        size_t gi = base + dt * 16 + lane15;
        ogb[gi] = f2bf(oacc[dt][r] * inv * bf2f(gb[gi]));
      }
    }
  }
  grid_sync(bar, bar + 32);

  // ---------------- stage 3: out gemm, 32x64 tile/block, K=512 ----------------
  {
    u16* As = (u16*)SM;           // 32 x 40
    u16* Bs = (u16*)(SM + 2560);  // 64 x 40
    const int rm0 = (bid & 127) * 32;
    const int cn0 = (bid >> 7) * 64;
    const int wm = (wave & 1) * 16, wn = (wave >> 1) * 32;
    const int rowA = tid >> 3, segA = (tid & 7) * 4;
    const int rowB = tid >> 2, segB = (tid & 3) * 8;
    floatx4 acc[2] = {};
    uint2 a0 = *(const uint2*)(ogb + (rm0 + rowA) * 512 + segA);
    uint4 b0 = *(const uint4*)(WoT + (cn0 + rowB) * 512 + segB);
#pragma unroll 1
    for (int k0 = 0; k0 < 512; k0 += 32) {
      __syncthreads();
      *(uint2*)(As + rowA * 40 + segA) = a0;
      *(uint4*)(Bs + rowB * 40 + segB) = b0;
      __syncthreads();
      if (k0 < 480) {
        a0 = *(const uint2*)(ogb + (rm0 + rowA) * 512 + k0 + 32 + segA);
        b0 = *(const uint4*)(WoT + (cn0 + rowB) * 512 + k0 + 32 + segB);
      }
      bf16x8 af = *(const bf16x8*)(As + (wm + lane15) * 40 + quad * 8);
      bf16x8 bfr[2];
#pragma unroll
      for (int nt = 0; nt < 2; ++nt) bfr[nt] = *(const bf16x8*)(Bs + (wn + nt * 16 + lane15) * 40 + quad * 8);
#pragma unroll
      for (int nt = 0; nt < 2; ++nt) acc[nt] = MFMA(af, bfr[nt], acc[nt]);
    }
#pragma unroll
    for (int nt = 0; nt < 2; ++nt) {
      int col = cn0 + wn + nt * 16 + lane15;
      float bv = bo[col];
#pragma unroll
      for (int r = 0; r < 4; ++r) {
        int row = rm0 + wm + quad * 4 + r;
        out[(size_t)row * 256 + col] = acc[nt][r] + bv;
      }
    }
  }
}

extern "C" void kernel_launch(void* const* d_in, const int* in_sizes, int n_in,
                              void* d_out, int out_size, void* d_ws, size_t ws_size,
                              hipStream_t stream) {
  const float* x = (const float*)d_in[0];
  const float* bias = (const float*)d_in[1];
  const float* Wq = (const float*)d_in[2];
  const float* Wkv = (const float*)d_in[3];
  const float* Wo = (const float*)d_in[4];
  const float* bo = (const float*)d_in[5];
  const float* Wg = (const float*)d_in[6];
  const float* bg = (const float*)d_in[7];
  float* out = (float*)d_out;
  char* ws = (char*)d_ws;
  u16* xb    = (u16*)(ws);                 // 2 MB
  u16* WcatT = (u16*)(ws + 2097152);       // 1 MB
  u16* WoT   = (u16*)(ws + 3145728);       // 256 KB
  u16* qb    = (u16*)(ws + 3407872);       // 4 MB
  u16* kfrag = (u16*)(ws + 7602176);       // 4 MB
  u16* vfrag = (u16*)(ws + 11796480);      // 4 MB
  u16* gb    = (u16*)(ws + 15990784);      // 4 MB
  u16* ogb   = (u16*)(ws + 20185088);      // 4 MB
  unsigned* bar = (unsigned*)(ws + 24379392);  // 256 B barrier state

  hipMemsetAsync(bar, 0, 256, stream);     // clear barrier after ws poison
  fused_pipeline_k<<<512, 256, 0, stream>>>(x, bias, Wq, Wkv, Wo, bo, Wg, bg,
                                            xb, WcatT, WoT, qb, kfrag, vfrag,
                                            gb, ogb, out, bar);
}

// Round 3
// 258.946 us; speedup vs baseline: 2.0733x; 2.0733x over previous
//
#include <hip/hip_runtime.h>

typedef unsigned short u16;
typedef unsigned int u32;
typedef __attribute__((ext_vector_type(8))) __bf16 bf16x8;
typedef __attribute__((ext_vector_type(4))) float floatx4;
typedef const __attribute__((address_space(1))) unsigned char glob_u8;
typedef __attribute__((address_space(3))) unsigned char lds_u8;

#define DEV __device__ __forceinline__

DEV u16 f2bf(float f) {
  u32 u = __builtin_bit_cast(u32, f);
  u = (u + 0x7fffu + ((u >> 16) & 1u)) >> 16;
  return (u16)u;
}
DEV float bf2f(u16 h) {
  u32 u = ((u32)h) << 16;
  return __builtin_bit_cast(float, u);
}
DEV floatx4 MFMA(bf16x8 a, bf16x8 b, floatx4 c) {
  return __builtin_amdgcn_mfma_f32_16x16x32_bf16(a, b, c, 0, 0, 0);
}

// ---------------- convert: x -> bf16, weights -> bf16 transposed -------------
__global__ void convert_k(const float* __restrict__ x, const float* __restrict__ Wq,
                          const float* __restrict__ Wkv, const float* __restrict__ Wg,
                          const float* __restrict__ Wo,
                          u16* __restrict__ xb, u16* __restrict__ WcatT, u16* __restrict__ WoT) {
  int i = blockIdx.x * 256 + threadIdx.x;
  if (i < 1048576) { xb[i] = f2bf(x[i]); return; }
  i -= 1048576;
  if (i < 524288) {
    int n = i >> 8, kk = i & 255;
    float v;
    if (n < 512) v = Wq[kk * 512 + n];
    else if (n < 1536) v = Wkv[kk * 1024 + (n - 512)];
    else v = Wg[kk * 512 + (n - 1536)];
    WcatT[i] = f2bf(v);
    return;
  }
  i -= 524288;
  if (i < 131072) {
    int n = i >> 9, kk = i & 511;
    WoT[i] = f2bf(Wo[kk * 256 + n]);
  }
}

// -------- GEMM1: 128x128 tiles (m97 structure); K/V in MFMA-fragment order ---
// 4 waves in 2x2; each wave 64x64 output = acc[4][4]; 16 MFMA + 8 ds_read_b128
// per K-step. Grid (32,16)=512 blocks -> 2 blocks/CU (grid-limited).
__global__ __launch_bounds__(256, 2) void gemm_qkvg(
    const u16* __restrict__ xb, const u16* __restrict__ WcatT, const float* __restrict__ bg,
    u16* __restrict__ qb, u16* __restrict__ kfrag, u16* __restrict__ vfrag, u16* __restrict__ gb) {
  __shared__ __attribute__((aligned(16))) u16 As[128 * 40];
  __shared__ __attribute__((aligned(16))) u16 Bs[128 * 40];
  const int tid = threadIdx.x;
  const int wave = tid >> 6, lane = tid & 63;
  const int lane15 = lane & 15, quad = lane >> 4;
  const int rm0 = blockIdx.x * 128;
  const int cn0 = blockIdx.y * 128;
  const int wm = (wave & 1) * 64, wn = (wave >> 1) * 64;
  const int rowS = tid >> 1, segS = (tid & 1) * 16;
  floatx4 acc[4][4] = {};
  uint4 a0 = *(const uint4*)(xb + (rm0 + rowS) * 256 + segS);
  uint4 a1 = *(const uint4*)(xb + (rm0 + rowS) * 256 + segS + 8);
  uint4 b0 = *(const uint4*)(WcatT + (cn0 + rowS) * 256 + segS);
  uint4 b1 = *(const uint4*)(WcatT + (cn0 + rowS) * 256 + segS + 8);
#pragma unroll 1
  for (int k0 = 0; k0 < 256; k0 += 32) {
    __syncthreads();
    *(uint4*)(As + rowS * 40 + segS) = a0;
    *(uint4*)(As + rowS * 40 + segS + 8) = a1;
    *(uint4*)(Bs + rowS * 40 + segS) = b0;
    *(uint4*)(Bs + rowS * 40 + segS + 8) = b1;
    __syncthreads();
    if (k0 < 224) {
      a0 = *(const uint4*)(xb + (rm0 + rowS) * 256 + k0 + 32 + segS);
      a1 = *(const uint4*)(xb + (rm0 + rowS) * 256 + k0 + 32 + segS + 8);
      b0 = *(const uint4*)(WcatT + (cn0 + rowS) * 256 + k0 + 32 + segS);
      b1 = *(const uint4*)(WcatT + (cn0 + rowS) * 256 + k0 + 32 + segS + 8);
    }
    bf16x8 af[4], bfr[4];
#pragma unroll
    for (int mt = 0; mt < 4; ++mt) af[mt] = *(const bf16x8*)(As + (wm + mt * 16 + lane15) * 40 + quad * 8);
#pragma unroll
    for (int nt = 0; nt < 4; ++nt) bfr[nt] = *(const bf16x8*)(Bs + (wn + nt * 16 + lane15) * 40 + quad * 8);
#pragma unroll
    for (int mt = 0; mt < 4; ++mt)
#pragma unroll
      for (int nt = 0; nt < 4; ++nt)
        acc[mt][nt] = MFMA(af[mt], bfr[nt], acc[mt][nt]);
  }
#pragma unroll
  for (int mt = 0; mt < 4; ++mt)
#pragma unroll
    for (int nt = 0; nt < 4; ++nt)
#pragma unroll
      for (int r = 0; r < 4; ++r) {
        int row = rm0 + wm + mt * 16 + quad * 4 + r;
        int col = cn0 + wn + nt * 16 + lane15;
        float v = acc[mt][nt][r];
        int b = row >> 10, n = row & 1023;
        if (col < 512) {
          int h = col >> 6, d = col & 63;
          qb[((b * 8 + h) * 1024 + n) * 64 + d] = f2bf(v * 0.125f);
        } else if (col < 1024) {
          int c = col - 512, h = c >> 6, d = c & 63;
          int bh2 = b * 8 + h;
          int t = n >> 4, l15 = n & 15;
          int half = d >> 5, qd = (d >> 3) & 3, e = d & 7;
          kfrag[(size_t)bh2 * 65536 + t * 1024 + half * 512 + (qd * 16 + l15) * 8 + e] = f2bf(v);
        } else if (col < 1536) {
          int c = col - 1024, h = c >> 6, d = c & 63;
          int bh2 = b * 8 + h;
          int t64 = n >> 6, ck = (n >> 5) & 1, qd = (n >> 3) & 3, e = n & 7;
          int dt = d >> 4, l15 = d & 15;
          vfrag[(size_t)bh2 * 65536 + t64 * 4096 + dt * 1024 + ck * 512 + (qd * 16 + l15) * 8 + e] = f2bf(v);
        } else {
          int c = col - 1536;
          float g = 1.0f / (1.0f + __expf(-(v + bg[c])));
          gb[row * 512 + c] = f2bf(g);
        }
      }
}

// ------- fused attention: full-K (1024 keys), double-buffered DMA pipeline ---
// grid (32,16)=512 blocks; 2 blocks/CU. Bias chunks padded to 1088 B so the
// softmax read's quad offsets land on banks {0,16,0,16} -> 2 lanes/bank (free)
// instead of the 4-way conflict of the 1024 B layout.
__global__ __launch_bounds__(256, 2) void attn_k(
    const u16* __restrict__ qb, const u16* __restrict__ kfrag, const u16* __restrict__ vfrag,
    const float* __restrict__ bias, const u16* __restrict__ gb, u16* __restrict__ ogb) {
  __shared__ __attribute__((aligned(16))) u16 Kt[2][4096];     // 2 x 8 KB frag-order keys
  __shared__ __attribute__((aligned(16))) u16 Vt[2][4096];     // 2 x 8 KB frag-order values
  __shared__ __attribute__((aligned(16))) float Btf[2][4352];  // 2 x 17 KB bias, 272 f/chunk
  __shared__ __attribute__((aligned(16))) u16 Ps[4 * 16 * 72];
  const int tid = threadIdx.x;
  const int wave = tid >> 6, lane = tid & 63;
  const int lane15 = lane & 15, quad = lane >> 4;
  const int bh = blockIdx.x;
  const int q0 = blockIdx.y * 64;

  bf16x8 qf0, qf1;
  {
    const u16* qrow = qb + ((size_t)(bh * 1024 + q0 + wave * 16 + lane15)) * 64 + quad * 8;
    qf0 = *(const bf16x8*)(qrow);
    qf1 = *(const bf16x8*)(qrow + 32);
  }
  bf16x8 ones;
#pragma unroll
  for (int e = 0; e < 8; ++e) ones[e] = __builtin_bit_cast(__bf16, (u16)0x3F80);

  floatx4 oacc[4] = {};
  floatx4 lacc = {};

  u16* Pw = Ps + wave * (16 * 72);
  const u16* kp = kfrag + (size_t)bh * 65536;
  const u16* vp = vfrag + (size_t)bh * 65536;

  // ---- DMA stage of one 64-key tile into buffer bufi (8 loads/wave) ----
  auto stage = [&](int kt, int bufi) {
    const int kb0 = kt * 64;
    const u16* kS = kp + kb0 * 64;
    const u16* vS = vp + kb0 * 64;
#pragma unroll
    for (int c = 0; c < 2; ++c) {
      int ch = wave * 2 + c;
      __builtin_amdgcn_global_load_lds((glob_u8*)(kS + ch * 512 + lane * 8),
                                       (lds_u8*)(&Kt[bufi][ch * 512]), 16, 0, 0);
      __builtin_amdgcn_global_load_lds((glob_u8*)(vS + ch * 512 + lane * 8),
                                       (lds_u8*)(&Vt[bufi][ch * 512]), 16, 0, 0);
    }
#pragma unroll
    for (int c = 0; c < 4; ++c) {
      int ch = wave * 4 + c;
      const float* bS = bias + ((size_t)(bh * 1024 + q0 + ch * 4 + quad)) * 1024 + kb0 + lane15 * 4;
      __builtin_amdgcn_global_load_lds((glob_u8*)bS, (lds_u8*)(&Btf[bufi][ch * 272]), 16, 0, 0);
    }
  };

  stage(0, 0);
  __syncthreads();   // implicit vmcnt(0): tile 0 resident
  int cur = 0;
#pragma unroll 1
  for (int kt = 0; kt < 16; ++kt) {
    if (kt < 15) stage(kt + 1, cur ^ 1);   // prefetch overlaps compute below
    const u16* Ktc = Kt[cur];
    const u16* Vtc = Vt[cur];
    const float* Btc = Btf[cur];
    // ---- S = Q K^T  (conflict-free lane*16 ds_read_b128) ----
    floatx4 s[4];
#pragma unroll
    for (int j = 0; j < 4; ++j) {
      bf16x8 kf0 = *(const bf16x8*)(Ktc + j * 1024 + lane * 8);
      bf16x8 kf1 = *(const bf16x8*)(Ktc + j * 1024 + 512 + lane * 8);
      floatx4 z = {};
      z = MFMA(qf0, kf0, z);
      s[j] = MFMA(qf1, kf1, z);
    }
    // ---- fixed-max softmax: p = exp(s + bias - 8); bias chunk stride 272 ----
#pragma unroll
    for (int j = 0; j < 4; ++j)
#pragma unroll
      for (int r = 0; r < 4; ++r)
        s[j][r] = __expf(s[j][r] + Btc[(wave * 4 + quad) * 272 + r * 64 + j * 16 + lane15] - 8.0f);
    // ---- P -> wave-private LDS (C-layout write, A-layout read) ----
#pragma unroll
    for (int j = 0; j < 4; ++j)
#pragma unroll
      for (int r = 0; r < 4; ++r)
        Pw[(quad * 4 + r) * 72 + j * 16 + lane15] = f2bf(s[j][r]);
    bf16x8 pf0 = *(const bf16x8*)(Pw + lane15 * 72 + quad * 8);
    bf16x8 pf1 = *(const bf16x8*)(Pw + lane15 * 72 + 32 + quad * 8);

    // ---- l += P·1 ; O += P·V ----
    lacc = MFMA(pf0, ones, lacc);
    lacc = MFMA(pf1, ones, lacc);
#pragma unroll
    for (int dt = 0; dt < 4; ++dt) {
      bf16x8 vf0 = *(const bf16x8*)(Vtc + dt * 1024 + lane * 8);
      bf16x8 vf1 = *(const bf16x8*)(Vtc + dt * 1024 + 512 + lane * 8);
      oacc[dt] = MFMA(pf0, vf0, oacc[dt]);
      oacc[dt] = MFMA(pf1, vf1, oacc[dt]);
    }
    __syncthreads();   // drains prefetch (vmcnt(0)) + protects buf[cur] reuse
    cur ^= 1;
  }

  // ---- fused epilogue: normalize by l, apply gate, write ogb bf16 ----
  const int b = bh >> 3, h = bh & 7;
#pragma unroll
  for (int r = 0; r < 4; ++r) {
    int q = q0 + wave * 16 + quad * 4 + r;
    float inv = 1.0f / lacc[r];
    size_t base = ((size_t)(b * 1024 + q)) * 512 + h * 64;
#pragma unroll
    for (int dt = 0; dt < 4; ++dt) {
      size_t gi = base + dt * 16 + lane15;
      ogb[gi] = f2bf(oacc[dt][r] * inv * bf2f(gb[gi]));
    }
  }
}

// ------- GEMM2: 32x64 tiles, 512 blocks (2/CU), full K=512, fused +bo --------
__global__ __launch_bounds__(256, 4) void gemm_out_k(
    const u16* __restrict__ og, const u16* __restrict__ WoT,
    const float* __restrict__ bo, float* __restrict__ out) {
  __shared__ __attribute__((aligned(16))) u16 As[32 * 40];
  __shared__ __attribute__((aligned(16))) u16 Bs[64 * 40];
  const int tid = threadIdx.x;
  const int wave = tid >> 6, lane = tid & 63;
  const int lane15 = lane & 15, quad = lane >> 4;
  const int rm0 = blockIdx.x * 32;
  const int cn0 = blockIdx.y * 64;
  const int wm = (wave & 1) * 16, wn = (wave >> 1) * 32;
  const int rowA = tid >> 3, segA = (tid & 7) * 4;
  const int rowB = tid >> 2, segB = (tid & 3) * 8;
  floatx4 acc[2] = {};
  uint2 a0 = *(const uint2*)(og + (rm0 + rowA) * 512 + segA);
  uint4 b0 = *(const uint4*)(WoT + (cn0 + rowB) * 512 + segB);
#pragma unroll 1
  for (int k0 = 0; k0 < 512; k0 += 32) {
    __syncthreads();
    *(uint2*)(As + rowA * 40 + segA) = a0;
    *(uint4*)(Bs + rowB * 40 + segB) = b0;
    __syncthreads();
    if (k0 < 480) {
      a0 = *(const uint2*)(og + (rm0 + rowA) * 512 + k0 + 32 + segA);
      b0 = *(const uint4*)(WoT + (cn0 + rowB) * 512 + k0 + 32 + segB);
    }
    bf16x8 af = *(const bf16x8*)(As + (wm + lane15) * 40 + quad * 8);
    bf16x8 bfr[2];
#pragma unroll
    for (int nt = 0; nt < 2; ++nt) bfr[nt] = *(const bf16x8*)(Bs + (wn + nt * 16 + lane15) * 40 + quad * 8);
#pragma unroll
    for (int nt = 0; nt < 2; ++nt) acc[nt] = MFMA(af, bfr[nt], acc[nt]);
  }
#pragma unroll
  for (int nt = 0; nt < 2; ++nt) {
    int col = cn0 + wn + nt * 16 + lane15;
    float bv = bo[col];
#pragma unroll
    for (int r = 0; r < 4; ++r) {
      int row = rm0 + wm + quad * 4 + r;
      out[(size_t)row * 256 + col] = acc[nt][r] + bv;
    }
  }
}

extern "C" void kernel_launch(void* const* d_in, const int* in_sizes, int n_in,
                              void* d_out, int out_size, void* d_ws, size_t ws_size,
                              hipStream_t stream) {
  const float* x = (const float*)d_in[0];
  const float* bias = (const float*)d_in[1];
  const float* Wq = (const float*)d_in[2];
  const float* Wkv = (const float*)d_in[3];
  const float* Wo = (const float*)d_in[4];
  const float* bo = (const float*)d_in[5];
  const float* Wg = (const float*)d_in[6];
  const float* bg = (const float*)d_in[7];
  float* out = (float*)d_out;
  char* ws = (char*)d_ws;
  u16* xb    = (u16*)(ws);                 // 2 MB
  u16* WcatT = (u16*)(ws + 2097152);       // 1 MB
  u16* WoT   = (u16*)(ws + 3145728);       // 256 KB
  u16* qb    = (u16*)(ws + 3407872);       // 4 MB
  u16* kfrag = (u16*)(ws + 7602176);       // 4 MB
  u16* vfrag = (u16*)(ws + 11796480);      // 4 MB
  u16* gb    = (u16*)(ws + 15990784);      // 4 MB
  u16* ogb   = (u16*)(ws + 20185088);      // 4 MB

  convert_k<<<6656, 256, 0, stream>>>(x, Wq, Wkv, Wg, Wo, xb, WcatT, WoT);
  dim3 g1(32, 16);
  gemm_qkvg<<<g1, 256, 0, stream>>>(xb, WcatT, bg, qb, kfrag, vfrag, gb);
  dim3 g2(32, 16);
  attn_k<<<g2, 256, 0, stream>>>(qb, kfrag, vfrag, bias, gb, ogb);
  dim3 g3(128, 4);
  gemm_out_k<<<g3, 256, 0, stream>>>(ogb, WoT, bo, out);
}

// Round 4
// 254.817 us; speedup vs baseline: 2.1069x; 1.0162x over previous
//
#include <hip/hip_runtime.h>

typedef unsigned short u16;
typedef unsigned int u32;
typedef __attribute__((ext_vector_type(8))) __bf16 bf16x8;
typedef __attribute__((ext_vector_type(4))) float floatx4;
typedef const __attribute__((address_space(1))) unsigned char glob_u8;
typedef __attribute__((address_space(3))) unsigned char lds_u8;

#define DEV __device__ __forceinline__

DEV u16 f2bf(float f) {
  return __builtin_bit_cast(u16, (__bf16)f);   // v_cvt (RNE) == manual round-to-nearest-even
}
DEV float bf2f(u16 h) {
  u32 u = ((u32)h) << 16;
  return __builtin_bit_cast(float, u);
}
DEV floatx4 MFMA(bf16x8 a, bf16x8 b, floatx4 c) {
  return __builtin_amdgcn_mfma_f32_16x16x32_bf16(a, b, c, 0, 0, 0);
}

// ---------------- convert: x -> bf16, weights -> bf16 transposed -------------
__global__ void convert_k(const float* __restrict__ x, const float* __restrict__ Wq,
                          const float* __restrict__ Wkv, const float* __restrict__ Wg,
                          const float* __restrict__ Wo,
                          u16* __restrict__ xb, u16* __restrict__ WcatT, u16* __restrict__ WoT) {
  int i = blockIdx.x * 256 + threadIdx.x;
  if (i < 1048576) { xb[i] = f2bf(x[i]); return; }
  i -= 1048576;
  if (i < 524288) {
    int n = i >> 8, kk = i & 255;
    float v;
    if (n < 512) v = Wq[kk * 512 + n];
    else if (n < 1536) v = Wkv[kk * 1024 + (n - 512)];
    else v = Wg[kk * 512 + (n - 1536)];
    WcatT[i] = f2bf(v);
    return;
  }
  i -= 524288;
  if (i < 131072) {
    int n = i >> 9, kk = i & 511;
    WoT[i] = f2bf(Wo[kk * 256 + n]);
  }
}

// -------- GEMM1: 128x64 tiles (round-1 proven config); K/V fragment order ----
__global__ __launch_bounds__(256, 4) void gemm_qkvg(
    const u16* __restrict__ xb, const u16* __restrict__ WcatT, const float* __restrict__ bg,
    u16* __restrict__ qb, u16* __restrict__ kfrag, u16* __restrict__ vfrag, u16* __restrict__ gb) {
  __shared__ __attribute__((aligned(16))) u16 As[128 * 40];
  __shared__ __attribute__((aligned(16))) u16 Bs[64 * 40];
  const int tid = threadIdx.x;
  const int wave = tid >> 6, lane = tid & 63;
  const int lane15 = lane & 15, quad = lane >> 4;
  const int rm0 = blockIdx.x * 128;
  const int cn0 = blockIdx.y * 64;
  const int wm = (wave & 1) * 64, wn = (wave >> 1) * 32;
  const int rowA = tid >> 1, segA = (tid & 1) * 16;
  const int rowB = tid >> 2, segB = (tid & 3) * 8;
  floatx4 acc[4][2] = {};
  uint4 a0 = *(const uint4*)(xb + (rm0 + rowA) * 256 + segA);
  uint4 a1 = *(const uint4*)(xb + (rm0 + rowA) * 256 + segA + 8);
  uint4 b0 = *(const uint4*)(WcatT + (cn0 + rowB) * 256 + segB);
#pragma unroll 1
  for (int k0 = 0; k0 < 256; k0 += 32) {
    __syncthreads();
    *(uint4*)(As + rowA * 40 + segA) = a0;
    *(uint4*)(As + rowA * 40 + segA + 8) = a1;
    *(uint4*)(Bs + rowB * 40 + segB) = b0;
    __syncthreads();
    if (k0 < 224) {
      a0 = *(const uint4*)(xb + (rm0 + rowA) * 256 + k0 + 32 + segA);
      a1 = *(const uint4*)(xb + (rm0 + rowA) * 256 + k0 + 32 + segA + 8);
      b0 = *(const uint4*)(WcatT + (cn0 + rowB) * 256 + k0 + 32 + segB);
    }
    bf16x8 af[4], bfr[2];
#pragma unroll
    for (int mt = 0; mt < 4; ++mt) af[mt] = *(const bf16x8*)(As + (wm + mt * 16 + lane15) * 40 + quad * 8);
#pragma unroll
    for (int nt = 0; nt < 2; ++nt) bfr[nt] = *(const bf16x8*)(Bs + (wn + nt * 16 + lane15) * 40 + quad * 8);
#pragma unroll
    for (int mt = 0; mt < 4; ++mt)
#pragma unroll
      for (int nt = 0; nt < 2; ++nt)
        acc[mt][nt] = MFMA(af[mt], bfr[nt], acc[mt][nt]);
  }
#pragma unroll
  for (int mt = 0; mt < 4; ++mt)
#pragma unroll
    for (int nt = 0; nt < 2; ++nt)
#pragma unroll
      for (int r = 0; r < 4; ++r) {
        int row = rm0 + wm + mt * 16 + quad * 4 + r;
        int col = cn0 + wn + nt * 16 + lane15;
        float v = acc[mt][nt][r];
        int b = row >> 10, n = row & 1023;
        if (col < 512) {
          int h = col >> 6, d = col & 63;
          qb[((b * 8 + h) * 1024 + n) * 64 + d] = f2bf(v * 0.125f);
        } else if (col < 1024) {
          int c = col - 512, h = c >> 6, d = c & 63;
          int bh2 = b * 8 + h;
          int t = n >> 4, l15 = n & 15;
          int half = d >> 5, qd = (d >> 3) & 3, e = d & 7;
          kfrag[(size_t)bh2 * 65536 + t * 1024 + half * 512 + (qd * 16 + l15) * 8 + e] = f2bf(v);
        } else if (col < 1536) {
          int c = col - 1024, h = c >> 6, d = c & 63;
          int bh2 = b * 8 + h;
          int t64 = n >> 6, ck = (n >> 5) & 1, qd = (n >> 3) & 3, e = n & 7;
          int dt = d >> 4, l15 = d & 15;
          vfrag[(size_t)bh2 * 65536 + t64 * 4096 + dt * 1024 + ck * 512 + (qd * 16 + l15) * 8 + e] = f2bf(v);
        } else {
          int c = col - 1536;
          float g = 1.0f / (1.0f + __expf(-(v + bg[c])));
          gb[row * 512 + c] = f2bf(g);
        }
      }
}

// ------- fused attention: full-K, K/V DMA double-buffer, bias in VGPRs -------
// LDS 41984 B -> 3 blocks/CU (12 waves/CU). Bias loaded per-lane as 16 scalar
// global_load_dword per tile (L3-resident), issued before QK^T, consumed in
// softmax -- no bias LDS, no bias DMA on the barrier-drain path.
__global__ __launch_bounds__(256, 3) void attn_k(
    const u16* __restrict__ qb, const u16* __restrict__ kfrag, const u16* __restrict__ vfrag,
    const float* __restrict__ bias, const u16* __restrict__ gb, u16* __restrict__ ogb) {
  __shared__ __attribute__((aligned(16))) u16 Kt[2][4096];   // 2 x 8 KB frag-order keys
  __shared__ __attribute__((aligned(16))) u16 Vt[2][4096];   // 2 x 8 KB frag-order values
  __shared__ __attribute__((aligned(16))) u16 Ps[4 * 16 * 72];
  const int tid = threadIdx.x;
  const int wave = tid >> 6, lane = tid & 63;
  const int lane15 = lane & 15, quad = lane >> 4;
  const int bh = blockIdx.x;
  const int q0 = blockIdx.y * 64;

  bf16x8 qf0, qf1;
  {
    const u16* qrow = qb + ((size_t)(bh * 1024 + q0 + wave * 16 + lane15)) * 64 + quad * 8;
    qf0 = *(const bf16x8*)(qrow);
    qf1 = *(const bf16x8*)(qrow + 32);
  }
  bf16x8 ones;
#pragma unroll
  for (int e = 0; e < 8; ++e) ones[e] = __builtin_bit_cast(__bf16, (u16)0x3F80);

  floatx4 oacc[4] = {};
  floatx4 lacc = {};

  u16* Pw = Ps + wave * (16 * 72);
  const u16* kp = kfrag + (size_t)bh * 65536;
  const u16* vp = vfrag + (size_t)bh * 65536;
  // per-lane bias base: row (q0 + wave*16 + quad*4), col lane15
  const float* bbase = bias + ((size_t)(bh * 1024 + q0 + wave * 16 + quad * 4)) * 1024 + lane15;

  // ---- DMA stage of one 64-key K/V tile into buffer bufi (4 loads/wave) ----
  auto stage = [&](int kt, int bufi) {
    const int kb0 = kt * 64;
    const u16* kS = kp + kb0 * 64;
    const u16* vS = vp + kb0 * 64;
#pragma unroll
    for (int c = 0; c < 2; ++c) {
      int ch = wave * 2 + c;
      __builtin_amdgcn_global_load_lds((glob_u8*)(kS + ch * 512 + lane * 8),
                                       (lds_u8*)(&Kt[bufi][ch * 512]), 16, 0, 0);
      __builtin_amdgcn_global_load_lds((glob_u8*)(vS + ch * 512 + lane * 8),
                                       (lds_u8*)(&Vt[bufi][ch * 512]), 16, 0, 0);
    }
  };

  stage(0, 0);
  __syncthreads();   // implicit vmcnt(0): tile 0 resident
  int cur = 0;
#pragma unroll 1
  for (int kt = 0; kt < 16; ++kt) {
    if (kt < 15) stage(kt + 1, cur ^ 1);   // prefetch overlaps compute below
    // ---- current tile's bias -> VGPRs (16 scalar loads, hidden under QK^T) ----
    float bv[4][4];
#pragma unroll
    for (int r = 0; r < 4; ++r)
#pragma unroll
      for (int j = 0; j < 4; ++j)
        bv[r][j] = bbase[r * 1024 + kt * 64 + j * 16];
    const u16* Ktc = Kt[cur];
    const u16* Vtc = Vt[cur];
    // ---- S = Q K^T  (conflict-free lane*16 ds_read_b128) ----
    floatx4 s[4];
#pragma unroll
    for (int j = 0; j < 4; ++j) {
      bf16x8 kf0 = *(const bf16x8*)(Ktc + j * 1024 + lane * 8);
      bf16x8 kf1 = *(const bf16x8*)(Ktc + j * 1024 + 512 + lane * 8);
      floatx4 z = {};
      z = MFMA(qf0, kf0, z);
      s[j] = MFMA(qf1, kf1, z);
    }
    // ---- fixed-max softmax: p = exp(s + bias - 8) ----
#pragma unroll
    for (int j = 0; j < 4; ++j)
#pragma unroll
      for (int r = 0; r < 4; ++r)
        s[j][r] = __expf(s[j][r] + bv[r][j] - 8.0f);
    // ---- P -> wave-private LDS (C-layout write, A-layout read) ----
#pragma unroll
    for (int j = 0; j < 4; ++j)
#pragma unroll
      for (int r = 0; r < 4; ++r)
        Pw[(quad * 4 + r) * 72 + j * 16 + lane15] = f2bf(s[j][r]);
    bf16x8 pf0 = *(const bf16x8*)(Pw + lane15 * 72 + quad * 8);
    bf16x8 pf1 = *(const bf16x8*)(Pw + lane15 * 72 + 32 + quad * 8);

    // ---- l += P·1 ; O += P·V ----
    lacc = MFMA(pf0, ones, lacc);
    lacc = MFMA(pf1, ones, lacc);
#pragma unroll
    for (int dt = 0; dt < 4; ++dt) {
      bf16x8 vf0 = *(const bf16x8*)(Vtc + dt * 1024 + lane * 8);
      bf16x8 vf1 = *(const bf16x8*)(Vtc + dt * 1024 + 512 + lane * 8);
      oacc[dt] = MFMA(pf0, vf0, oacc[dt]);
      oacc[dt] = MFMA(pf1, vf1, oacc[dt]);
    }
    __syncthreads();   // drains prefetch (vmcnt(0)) + protects buf[cur] reuse
    cur ^= 1;
  }

  // ---- fused epilogue: normalize by l, apply gate, write ogb bf16 ----
  const int b = bh >> 3, h = bh & 7;
#pragma unroll
  for (int r = 0; r < 4; ++r) {
    int q = q0 + wave * 16 + quad * 4 + r;
    float inv = 1.0f / lacc[r];
    size_t base = ((size_t)(b * 1024 + q)) * 512 + h * 64;
#pragma unroll
    for (int dt = 0; dt < 4; ++dt) {
      size_t gi = base + dt * 16 + lane15;
      ogb[gi] = f2bf(oacc[dt][r] * inv * bf2f(gb[gi]));
    }
  }
}

// ------- GEMM2: 64x64 tiles (round-1 proven config), full K=512, fused +bo ---
__global__ __launch_bounds__(256, 4) void gemm_out_k(
    const u16* __restrict__ og, const u16* __restrict__ WoT,
    const float* __restrict__ bo, float* __restrict__ out) {
  __shared__ __attribute__((aligned(16))) u16 As[64 * 40];
  __shared__ __attribute__((aligned(16))) u16 Bs[64 * 40];
  const int tid = threadIdx.x;
  const int wave = tid >> 6, lane = tid & 63;
  const int lane15 = lane & 15, quad = lane >> 4;
  const int rm0 = blockIdx.x * 64;
  const int cn0 = blockIdx.y * 64;
  const int wm = (wave & 1) * 32, wn = (wave >> 1) * 32;
  const int rowA = tid >> 2, segA = (tid & 3) * 8;
  floatx4 acc[2][2] = {};
  uint4 a0 = *(const uint4*)(og + (rm0 + rowA) * 512 + segA);
  uint4 b0 = *(const uint4*)(WoT + (cn0 + rowA) * 512 + segA);
#pragma unroll 1
  for (int k0 = 0; k0 < 512; k0 += 32) {
    __syncthreads();
    *(uint4*)(As + rowA * 40 + segA) = a0;
    *(uint4*)(Bs + rowA * 40 + segA) = b0;
    __syncthreads();
    if (k0 < 480) {
      a0 = *(const uint4*)(og + (rm0 + rowA) * 512 + k0 + 32 + segA);
      b0 = *(const uint4*)(WoT + (cn0 + rowA) * 512 + k0 + 32 + segA);
    }
    bf16x8 af[2], bfr[2];
#pragma unroll
    for (int mt = 0; mt < 2; ++mt) af[mt] = *(const bf16x8*)(As + (wm + mt * 16 + lane15) * 40 + quad * 8);
#pragma unroll
    for (int nt = 0; nt < 2; ++nt) bfr[nt] = *(const bf16x8*)(Bs + (wn + nt * 16 + lane15) * 40 + quad * 8);
#pragma unroll
    for (int mt = 0; mt < 2; ++mt)
#pragma unroll
      for (int nt = 0; nt < 2; ++nt)
        acc[mt][nt] = MFMA(af[mt], bfr[nt], acc[mt][nt]);
  }
#pragma unroll
  for (int nt = 0; nt < 2; ++nt) {
    int col = cn0 + wn + nt * 16 + lane15;
    float bv = bo[col];
#pragma unroll
    for (int mt = 0; mt < 2; ++mt)
#pragma unroll
      for (int r = 0; r < 4; ++r) {
        int row = rm0 + wm + mt * 16 + quad * 4 + r;
        out[(size_t)row * 256 + col] = acc[mt][nt][r] + bv;
      }
  }
}

extern "C" void kernel_launch(void* const* d_in, const int* in_sizes, int n_in,
                              void* d_out, int out_size, void* d_ws, size_t ws_size,
                              hipStream_t stream) {
  const float* x = (const float*)d_in[0];
  const float* bias = (const float*)d_in[1];
  const float* Wq = (const float*)d_in[2];
  const float* Wkv = (const float*)d_in[3];
  const float* Wo = (const float*)d_in[4];
  const float* bo = (const float*)d_in[5];
  const float* Wg = (const float*)d_in[6];
  const float* bg = (const float*)d_in[7];
  float* out = (float*)d_out;
  char* ws = (char*)d_ws;
  u16* xb    = (u16*)(ws);                 // 2 MB
  u16* WcatT = (u16*)(ws + 2097152);       // 1 MB
  u16* WoT   = (u16*)(ws + 3145728);       // 256 KB
  u16* qb    = (u16*)(ws + 3407872);       // 4 MB
  u16* kfrag = (u16*)(ws + 7602176);       // 4 MB
  u16* vfrag = (u16*)(ws + 11796480);      // 4 MB
  u16* gb    = (u16*)(ws + 15990784);      // 4 MB
  u16* ogb   = (u16*)(ws + 20185088);      // 4 MB

  convert_k<<<6656, 256, 0, stream>>>(x, Wq, Wkv, Wg, Wo, xb, WcatT, WoT);
  dim3 g1(32, 32);
  gemm_qkvg<<<g1, 256, 0, stream>>>(xb, WcatT, bg, qb, kfrag, vfrag, gb);
  dim3 g2(32, 16);
  attn_k<<<g2, 256, 0, stream>>>(qb, kfrag, vfrag, bias, gb, ogb);
  dim3 g3(64, 4);
  gemm_out_k<<<g3, 256, 0, stream>>>(ogb, WoT, bo, out);
}

// Round 5
// 253.256 us; speedup vs baseline: 2.1198x; 1.0062x over previous
//
#include <hip/hip_runtime.h>

typedef unsigned short u16;
typedef unsigned int u32;
typedef __attribute__((ext_vector_type(8))) __bf16 bf16x8;
typedef __attribute__((ext_vector_type(4))) float floatx4;
typedef const __attribute__((address_space(1))) unsigned char glob_u8;
typedef __attribute__((address_space(3))) unsigned char lds_u8;

#define DEV __device__ __forceinline__

DEV u16 f2bf(float f) {
  return __builtin_bit_cast(u16, (__bf16)f);   // v_cvt (RNE) == manual round-to-nearest-even
}
DEV float bf2f(u16 h) {
  u32 u = ((u32)h) << 16;
  return __builtin_bit_cast(float, u);
}
DEV floatx4 MFMA(bf16x8 a, bf16x8 b, floatx4 c) {
  return __builtin_amdgcn_mfma_f32_16x16x32_bf16(a, b, c, 0, 0, 0);
}

// ---------------- convert: x -> bf16, weights -> bf16 transposed -------------
__global__ void convert_k(const float* __restrict__ x, const float* __restrict__ Wq,
                          const float* __restrict__ Wkv, const float* __restrict__ Wg,
                          const float* __restrict__ Wo,
                          u16* __restrict__ xb, u16* __restrict__ WcatT, u16* __restrict__ WoT) {
  int i = blockIdx.x * 256 + threadIdx.x;
  if (i < 1048576) { xb[i] = f2bf(x[i]); return; }
  i -= 1048576;
  if (i < 524288) {
    int n = i >> 8, kk = i & 255;
    float v;
    if (n < 512) v = Wq[kk * 512 + n];
    else if (n < 1536) v = Wkv[kk * 1024 + (n - 512)];
    else v = Wg[kk * 512 + (n - 1536)];
    WcatT[i] = f2bf(v);
    return;
  }
  i -= 524288;
  if (i < 131072) {
    int n = i >> 9, kk = i & 511;
    WoT[i] = f2bf(Wo[kk * 256 + n]);
  }
}

// -------- GEMM1: 128x64 tiles (round-1 proven config); K/V fragment order ----
__global__ __launch_bounds__(256, 4) void gemm_qkvg(
    const u16* __restrict__ xb, const u16* __restrict__ WcatT, const float* __restrict__ bg,
    u16* __restrict__ qb, u16* __restrict__ kfrag, u16* __restrict__ vfrag, u16* __restrict__ gb) {
  __shared__ __attribute__((aligned(16))) u16 As[128 * 40];
  __shared__ __attribute__((aligned(16))) u16 Bs[64 * 40];
  const int tid = threadIdx.x;
  const int wave = tid >> 6, lane = tid & 63;
  const int lane15 = lane & 15, quad = lane >> 4;
  const int rm0 = blockIdx.x * 128;
  const int cn0 = blockIdx.y * 64;
  const int wm = (wave & 1) * 64, wn = (wave >> 1) * 32;
  const int rowA = tid >> 1, segA = (tid & 1) * 16;
  const int rowB = tid >> 2, segB = (tid & 3) * 8;
  floatx4 acc[4][2] = {};
  uint4 a0 = *(const uint4*)(xb + (rm0 + rowA) * 256 + segA);
  uint4 a1 = *(const uint4*)(xb + (rm0 + rowA) * 256 + segA + 8);
  uint4 b0 = *(const uint4*)(WcatT + (cn0 + rowB) * 256 + segB);
#pragma unroll 1
  for (int k0 = 0; k0 < 256; k0 += 32) {
    __syncthreads();
    *(uint4*)(As + rowA * 40 + segA) = a0;
    *(uint4*)(As + rowA * 40 + segA + 8) = a1;
    *(uint4*)(Bs + rowB * 40 + segB) = b0;
    __syncthreads();
    if (k0 < 224) {
      a0 = *(const uint4*)(xb + (rm0 + rowA) * 256 + k0 + 32 + segA);
      a1 = *(const uint4*)(xb + (rm0 + rowA) * 256 + k0 + 32 + segA + 8);
      b0 = *(const uint4*)(WcatT + (cn0 + rowB) * 256 + k0 + 32 + segB);
    }
    bf16x8 af[4], bfr[2];
#pragma unroll
    for (int mt = 0; mt < 4; ++mt) af[mt] = *(const bf16x8*)(As + (wm + mt * 16 + lane15) * 40 + quad * 8);
#pragma unroll
    for (int nt = 0; nt < 2; ++nt) bfr[nt] = *(const bf16x8*)(Bs + (wn + nt * 16 + lane15) * 40 + quad * 8);
#pragma unroll
    for (int mt = 0; mt < 4; ++mt)
#pragma unroll
      for (int nt = 0; nt < 2; ++nt)
        acc[mt][nt] = MFMA(af[mt], bfr[nt], acc[mt][nt]);
  }
#pragma unroll
  for (int mt = 0; mt < 4; ++mt)
#pragma unroll
    for (int nt = 0; nt < 2; ++nt)
#pragma unroll
      for (int r = 0; r < 4; ++r) {
        int row = rm0 + wm + mt * 16 + quad * 4 + r;
        int col = cn0 + wn + nt * 16 + lane15;
        float v = acc[mt][nt][r];
        int b = row >> 10, n = row & 1023;
        if (col < 512) {
          int h = col >> 6, d = col & 63;
          qb[((b * 8 + h) * 1024 + n) * 64 + d] = f2bf(v * 0.125f);
        } else if (col < 1024) {
          int c = col - 512, h = c >> 6, d = c & 63;
          int bh2 = b * 8 + h;
          int t = n >> 4, l15 = n & 15;
          int half = d >> 5, qd = (d >> 3) & 3, e = d & 7;
          kfrag[(size_t)bh2 * 65536 + t * 1024 + half * 512 + (qd * 16 + l15) * 8 + e] = f2bf(v);
        } else if (col < 1536) {
          int c = col - 1024, h = c >> 6, d = c & 63;
          int bh2 = b * 8 + h;
          int t64 = n >> 6, ck = (n >> 5) & 1, qd = (n >> 3) & 3, e = n & 7;
          int dt = d >> 4, l15 = d & 15;
          vfrag[(size_t)bh2 * 65536 + t64 * 4096 + dt * 1024 + ck * 512 + (qd * 16 + l15) * 8 + e] = f2bf(v);
        } else {
          int c = col - 1536;
          float g = 1.0f / (1.0f + __expf(-(v + bg[c])));
          gb[row * 512 + c] = f2bf(g);
        }
      }
}

// ------- fused attention: 32 q-rows/block, grid (32,32)=1024 -> 4 blocks/CU --
// 4 waves = 2 q-sub-tiles x 2 key-halves; each wave computes a 16q x 32k P
// strip (9 MFMA/tile). Key-halves merged once at the end via LDS reduction.
// LDS 38 KB (K/V dbuf 32 KB + P 5 KB); bias per-lane in VGPRs (8 loads/tile).
__global__ __launch_bounds__(256, 4) void attn_k(
    const u16* __restrict__ qb, const u16* __restrict__ kfrag, const u16* __restrict__ vfrag,
    const float* __restrict__ bias, const u16* __restrict__ gb, u16* __restrict__ ogb) {
  __shared__ __attribute__((aligned(16))) u16 Kt[2][4096];   // 2 x 8 KB frag-order keys
  __shared__ __attribute__((aligned(16))) u16 Vt[2][4096];   // 2 x 8 KB frag-order values
  __shared__ __attribute__((aligned(16))) u16 Ps[4 * 16 * 40];
  const int tid = threadIdx.x;
  const int wave = tid >> 6, lane = tid & 63;
  const int lane15 = lane & 15, quad = lane >> 4;
  const int bh = blockIdx.x;
  const int q0 = blockIdx.y * 32;
  const int qw = (wave & 1) * 16;   // wave's q-sub-tile
  const int kh = wave >> 1;         // wave's 32-key half of each 64-key tile

  bf16x8 qf0, qf1;
  {
    const u16* qrow = qb + ((size_t)(bh * 1024 + q0 + qw + lane15)) * 64 + quad * 8;
    qf0 = *(const bf16x8*)(qrow);
    qf1 = *(const bf16x8*)(qrow + 32);
  }
  bf16x8 ones;
#pragma unroll
  for (int e = 0; e < 8; ++e) ones[e] = __builtin_bit_cast(__bf16, (u16)0x3F80);

  floatx4 oacc[4] = {};
  floatx4 lacc = {};

  u16* Pw = Ps + wave * (16 * 40);
  const u16* kp = kfrag + (size_t)bh * 65536;
  const u16* vp = vfrag + (size_t)bh * 65536;
  // per-lane bias base: row (q0 + qw + quad*4), col lane15
  const float* bbase = bias + ((size_t)(bh * 1024 + q0 + qw + quad * 4)) * 1024 + kh * 32 + lane15;

  // ---- DMA stage of one 64-key K/V tile into buffer bufi (4 loads/wave) ----
  auto stage = [&](int kt, int bufi) {
    const u16* kS = kp + kt * 4096;
    const u16* vS = vp + kt * 4096;
#pragma unroll
    for (int c = 0; c < 2; ++c) {
      int ch = wave * 2 + c;
      __builtin_amdgcn_global_load_lds((glob_u8*)(kS + ch * 512 + lane * 8),
                                       (lds_u8*)(&Kt[bufi][ch * 512]), 16, 0, 0);
      __builtin_amdgcn_global_load_lds((glob_u8*)(vS + ch * 512 + lane * 8),
                                       (lds_u8*)(&Vt[bufi][ch * 512]), 16, 0, 0);
    }
  };

  stage(0, 0);
  __syncthreads();   // implicit vmcnt(0): tile 0 resident
  int cur = 0;
#pragma unroll 1
  for (int kt = 0; kt < 16; ++kt) {
    if (kt < 15) stage(kt + 1, cur ^ 1);   // prefetch overlaps compute below
    // ---- this tile's bias -> VGPRs (8 scalar loads, hidden under QK^T) ----
    float bv[4][2];
#pragma unroll
    for (int r = 0; r < 4; ++r)
#pragma unroll
      for (int j = 0; j < 2; ++j)
        bv[r][j] = bbase[r * 1024 + kt * 64 + j * 16];
    const u16* Ktc = Kt[cur];
    const u16* Vtc = Vt[cur];
    // ---- S = Q K^T for this wave's 32-key half ----
    floatx4 s[2];
#pragma unroll
    for (int j = 0; j < 2; ++j) {
      const u16* kb = Ktc + (kh * 2 + j) * 1024 + lane * 8;
      bf16x8 kf0 = *(const bf16x8*)(kb);
      bf16x8 kf1 = *(const bf16x8*)(kb + 512);
      floatx4 z = {};
      z = MFMA(qf0, kf0, z);
      s[j] = MFMA(qf1, kf1, z);
    }
    // ---- fixed-max softmax: p = exp(s + bias - 8) ----
#pragma unroll
    for (int j = 0; j < 2; ++j)
#pragma unroll
      for (int r = 0; r < 4; ++r)
        s[j][r] = __expf(s[j][r] + bv[r][j] - 8.0f);
    // ---- P strip (16q x 32k) -> wave-private LDS ----
#pragma unroll
    for (int j = 0; j < 2; ++j)
#pragma unroll
      for (int r = 0; r < 4; ++r)
        Pw[(quad * 4 + r) * 40 + j * 16 + lane15] = f2bf(s[j][r]);
    bf16x8 pf = *(const bf16x8*)(Pw + lane15 * 40 + quad * 8);

    // ---- l += P·1 ; O += P·V (this wave's 32-key chunk = ck kh) ----
    lacc = MFMA(pf, ones, lacc);
#pragma unroll
    for (int dt = 0; dt < 4; ++dt) {
      bf16x8 vf = *(const bf16x8*)(Vtc + dt * 1024 + kh * 512 + lane * 8);
      oacc[dt] = MFMA(pf, vf, oacc[dt]);
    }
    __syncthreads();   // drains prefetch (vmcnt(0)) + protects buf[cur] reuse
    cur ^= 1;
  }

  // ---- combine key-halves: waves 2,3 -> LDS; waves 0,1 add ----
  float* red = (float*)Kt;   // 2 x 64 x 20 floats = 10 KB, fits in Kt
  if (wave >= 2) {
    float* r0 = red + (wave - 2) * 1280 + lane * 20;
#pragma unroll
    for (int dt = 0; dt < 4; ++dt)
#pragma unroll
      for (int r = 0; r < 4; ++r) r0[dt * 4 + r] = oacc[dt][r];
#pragma unroll
    for (int r = 0; r < 4; ++r) r0[16 + r] = lacc[r];
  }
  __syncthreads();
  if (wave < 2) {
    const float* r0 = red + wave * 1280 + lane * 20;
#pragma unroll
    for (int dt = 0; dt < 4; ++dt)
#pragma unroll
      for (int r = 0; r < 4; ++r) oacc[dt][r] += r0[dt * 4 + r];
#pragma unroll
    for (int r = 0; r < 4; ++r) lacc[r] += r0[16 + r];

    // ---- fused epilogue: normalize by l, apply gate, write ogb bf16 ----
    const int b = bh >> 3, h = bh & 7;
#pragma unroll
    for (int r = 0; r < 4; ++r) {
      int q = q0 + wave * 16 + quad * 4 + r;
      float inv = 1.0f / lacc[r];
      size_t base = ((size_t)(b * 1024 + q)) * 512 + h * 64;
#pragma unroll
      for (int dt = 0; dt < 4; ++dt) {
        size_t gi = base + dt * 16 + lane15;
        ogb[gi] = f2bf(oacc[dt][r] * inv * bf2f(gb[gi]));
      }
    }
  }
}

// ------- GEMM2: 64x64 tiles (round-1 proven config), full K=512, fused +bo ---
__global__ __launch_bounds__(256, 4) void gemm_out_k(
    const u16* __restrict__ og, const u16* __restrict__ WoT,
    const float* __restrict__ bo, float* __restrict__ out) {
  __shared__ __attribute__((aligned(16))) u16 As[64 * 40];
  __shared__ __attribute__((aligned(16))) u16 Bs[64 * 40];
  const int tid = threadIdx.x;
  const int wave = tid >> 6, lane = tid & 63;
  const int lane15 = lane & 15, quad = lane >> 4;
  const int rm0 = blockIdx.x * 64;
  const int cn0 = blockIdx.y * 64;
  const int wm = (wave & 1) * 32, wn = (wave >> 1) * 32;
  const int rowA = tid >> 2, segA = (tid & 3) * 8;
  floatx4 acc[2][2] = {};
  uint4 a0 = *(const uint4*)(og + (rm0 + rowA) * 512 + segA);
  uint4 b0 = *(const uint4*)(WoT + (cn0 + rowA) * 512 + segA);
#pragma unroll 1
  for (int k0 = 0; k0 < 512; k0 += 32) {
    __syncthreads();
    *(uint4*)(As + rowA * 40 + segA) = a0;
    *(uint4*)(Bs + rowA * 40 + segA) = b0;
    __syncthreads();
    if (k0 < 480) {
      a0 = *(const uint4*)(og + (rm0 + rowA) * 512 + k0 + 32 + segA);
      b0 = *(const uint4*)(WoT + (cn0 + rowA) * 512 + k0 + 32 + segA);
    }
    bf16x8 af[2], bfr[2];
#pragma unroll
    for (int mt = 0; mt < 2; ++mt) af[mt] = *(const bf16x8*)(As + (wm + mt * 16 + lane15) * 40 + quad * 8);
#pragma unroll
    for (int nt = 0; nt < 2; ++nt) bfr[nt] = *(const bf16x8*)(Bs + (wn + nt * 16 + lane15) * 40 + quad * 8);
#pragma unroll
    for (int mt = 0; mt < 2; ++mt)
#pragma unroll
      for (int nt = 0; nt < 2; ++nt)
        acc[mt][nt] = MFMA(af[mt], bfr[nt], acc[mt][nt]);
  }
#pragma unroll
  for (int nt = 0; nt < 2; ++nt) {
    int col = cn0 + wn + nt * 16 + lane15;
    float bv = bo[col];
#pragma unroll
    for (int mt = 0; mt < 2; ++mt)
#pragma unroll
      for (int r = 0; r < 4; ++r) {
        int row = rm0 + wm + mt * 16 + quad * 4 + r;
        out[(size_t)row * 256 + col] = acc[mt][nt][r] + bv;
      }
  }
}

extern "C" void kernel_launch(void* const* d_in, const int* in_sizes, int n_in,
                              void* d_out, int out_size, void* d_ws, size_t ws_size,
                              hipStream_t stream) {
  const float* x = (const float*)d_in[0];
  const float* bias = (const float*)d_in[1];
  const float* Wq = (const float*)d_in[2];
  const float* Wkv = (const float*)d_in[3];
  const float* Wo = (const float*)d_in[4];
  const float* bo = (const float*)d_in[5];
  const float* Wg = (const float*)d_in[6];
  const float* bg = (const float*)d_in[7];
  float* out = (float*)d_out;
  char* ws = (char*)d_ws;
  u16* xb    = (u16*)(ws);                 // 2 MB
  u16* WcatT = (u16*)(ws + 2097152);       // 1 MB
  u16* WoT   = (u16*)(ws + 3145728);       // 256 KB
  u16* qb    = (u16*)(ws + 3407872);       // 4 MB
  u16* kfrag = (u16*)(ws + 7602176);       // 4 MB
  u16* vfrag = (u16*)(ws + 11796480);      // 4 MB
  u16* gb    = (u16*)(ws + 15990784);      // 4 MB
  u16* ogb   = (u16*)(ws + 20185088);      // 4 MB

  convert_k<<<6656, 256, 0, stream>>>(x, Wq, Wkv, Wg, Wo, xb, WcatT, WoT);
  dim3 g1(32, 32);
  gemm_qkvg<<<g1, 256, 0, stream>>>(xb, WcatT, bg, qb, kfrag, vfrag, gb);
  dim3 g2(32, 32);
  attn_k<<<g2, 256, 0, stream>>>(qb, kfrag, vfrag, bias, gb, ogb);
  dim3 g3(64, 4);
  gemm_out_k<<<g3, 256, 0, stream>>>(ogb, WoT, bo, out);
}

// Round 6
// 248.032 us; speedup vs baseline: 2.1645x; 1.0211x over previous
//
#include <hip/hip_runtime.h>

typedef unsigned short u16;
typedef unsigned int u32;
typedef __attribute__((ext_vector_type(8))) __bf16 bf16x8;
typedef __attribute__((ext_vector_type(4))) float floatx4;
typedef const __attribute__((address_space(1))) unsigned char glob_u8;
typedef __attribute__((address_space(3))) unsigned char lds_u8;

#define DEV __device__ __forceinline__

DEV u16 f2bf(float f) {
  return __builtin_bit_cast(u16, (__bf16)f);   // v_cvt (RNE) == manual round-to-nearest-even
}
DEV float bf2f(u16 h) {
  u32 u = ((u32)h) << 16;
  return __builtin_bit_cast(float, u);
}
DEV floatx4 MFMA(bf16x8 a, bf16x8 b, floatx4 c) {
  return __builtin_amdgcn_mfma_f32_16x16x32_bf16(a, b, c, 0, 0, 0);
}

// ---------------- convert: x/weights -> bf16 in MFMA-fragment-tile order -----
// xA: 256 tiles (rb 0..31, kb 0..7), tile = 4096 u16 laid [r4][q][l15][e]
//     element (row = rb*128 + r4*16 + l15, k = kb*32 + q*8 + e)
// WB: 256 tiles (nb 0..31, kb 0..7), tile = 2048 u16 laid [n4][q][l15][e]
//     element (n = nb*64 + n4*16 + l15, k = kb*32 + q*8 + e), B[n][k] = W[k][n]
// WoT: unchanged row-major transposed layout (consumed by gemm_out_k).
__global__ void convert_k(const float* __restrict__ x, const float* __restrict__ Wq,
                          const float* __restrict__ Wkv, const float* __restrict__ Wg,
                          const float* __restrict__ Wo,
                          u16* __restrict__ xA, u16* __restrict__ WB, u16* __restrict__ WoT) {
  int i = blockIdx.x * 256 + threadIdx.x;
  if (i < 131072) {           // xA chunks (8 u16 each)
    int tile = i >> 9, w = i & 511;
    int g = w >> 6, q = (w >> 4) & 3, l15 = w & 15;
    int rb = tile >> 3, kb = tile & 7;
    int row = rb * 128 + g * 16 + l15;
    int k0 = kb * 32 + q * 8;
    float4 v0 = *(const float4*)(x + row * 256 + k0);
    float4 v1 = *(const float4*)(x + row * 256 + k0 + 4);
    u16 o[8] = {f2bf(v0.x), f2bf(v0.y), f2bf(v0.z), f2bf(v0.w),
                f2bf(v1.x), f2bf(v1.y), f2bf(v1.z), f2bf(v1.w)};
    *(uint4*)(xA + (size_t)i * 8) = *(uint4*)o;
    return;
  }
  i -= 131072;
  if (i < 65536) {            // WB chunks
    int tile = i >> 8, w = i & 255;
    int g = (w >> 6) & 3, q = (w >> 4) & 3, l15 = w & 15;
    int nb = tile >> 3, kb = tile & 7;
    int n = nb * 64 + g * 16 + l15;
    int k0 = kb * 32 + q * 8;
    u16 o[8];
#pragma unroll
    for (int e = 0; e < 8; ++e) {
      int k = k0 + e;
      float v;
      if (n < 512) v = Wq[k * 512 + n];
      else if (n < 1536) v = Wkv[k * 1024 + (n - 512)];
      else v = Wg[k * 512 + (n - 1536)];
      o[e] = f2bf(v);
    }
    *(uint4*)(WB + (size_t)i * 8) = *(uint4*)o;
    return;
  }
  i -= 65536;
  if (i < 131072) {           // WoT elements (old layout)
    int n = i >> 9, kk = i & 511;
    WoT[i] = f2bf(Wo[kk * 256 + n]);
  }
}

// -------- GEMM1: 128x64 tiles, DMA-staged frag-order operands, dbuf ----------
// Per K-step/wave: 3 global_load_lds (16B), 6 conflict-free ds_read_b128
// (lane*16 contiguous), 8 MFMA. LDS 24 KB; grid (32,32)=1024 -> 4 blocks/CU.
__global__ __launch_bounds__(256, 4) void gemm_qkvg(
    const u16* __restrict__ xA, const u16* __restrict__ WB, const float* __restrict__ bg,
    u16* __restrict__ qb, u16* __restrict__ kfrag, u16* __restrict__ vfrag, u16* __restrict__ gb) {
  __shared__ __attribute__((aligned(16))) u16 As[2][4096];   // 2 x 8 KB A frag-tiles
  __shared__ __attribute__((aligned(16))) u16 Bs[2][2048];   // 2 x 4 KB B frag-tiles
  const int tid = threadIdx.x;
  const int wave = tid >> 6, lane = tid & 63;
  const int lane15 = lane & 15, quad = lane >> 4;
  const int rb = blockIdx.x;            // 128-row block
  const int nb = blockIdx.y;            // 64-col block
  const int rm0 = rb * 128;
  const int cn0 = nb * 64;
  const int wm = (wave & 1) * 64, wn = (wave >> 1) * 32;
  const int ga = (wave & 1) * 4;        // A fragment-group base for this wave
  const int gb2 = (wave >> 1) * 2;      // B fragment-group base for this wave

  floatx4 acc[4][2] = {};

  auto stage = [&](int kb, int bufi) {
    const u16* At = xA + ((size_t)(rb * 8 + kb)) * 4096;
    const u16* Bt = WB + ((size_t)(nb * 8 + kb)) * 2048;
#pragma unroll
    for (int c = 0; c < 2; ++c) {
      int ch = wave * 2 + c;
      __builtin_amdgcn_global_load_lds((glob_u8*)(At + ch * 512 + lane * 8),
                                       (lds_u8*)(&As[bufi][ch * 512]), 16, 0, 0);
    }
    __builtin_amdgcn_global_load_lds((glob_u8*)(Bt + wave * 512 + lane * 8),
                                     (lds_u8*)(&Bs[bufi][wave * 512]), 16, 0, 0);
  };

  stage(0, 0);
  __syncthreads();   // implicit vmcnt(0): tile 0 resident
  int cur = 0;
#pragma unroll 1
  for (int kb = 0; kb < 8; ++kb) {
    if (kb < 7) stage(kb + 1, cur ^ 1);   // prefetch overlaps compute
    const u16* Ac = As[cur];
    const u16* Bc = Bs[cur];
    bf16x8 af[4], bfr[2];
#pragma unroll
    for (int mt = 0; mt < 4; ++mt) af[mt] = *(const bf16x8*)(Ac + ((ga + mt) * 64 + lane) * 8);
#pragma unroll
    for (int nt = 0; nt < 2; ++nt) bfr[nt] = *(const bf16x8*)(Bc + ((gb2 + nt) * 64 + lane) * 8);
#pragma unroll
    for (int mt = 0; mt < 4; ++mt)
#pragma unroll
      for (int nt = 0; nt < 2; ++nt)
        acc[mt][nt] = MFMA(af[mt], bfr[nt], acc[mt][nt]);
    __syncthreads();   // drains prefetch + protects buf reuse
    cur ^= 1;
  }
#pragma unroll
  for (int mt = 0; mt < 4; ++mt)
#pragma unroll
    for (int nt = 0; nt < 2; ++nt)
#pragma unroll
      for (int r = 0; r < 4; ++r) {
        int row = rm0 + wm + mt * 16 + quad * 4 + r;
        int col = cn0 + wn + nt * 16 + lane15;
        float v = acc[mt][nt][r];
        int b = row >> 10, n = row & 1023;
        if (col < 512) {
          int h = col >> 6, d = col & 63;
          qb[((b * 8 + h) * 1024 + n) * 64 + d] = f2bf(v * 0.125f);
        } else if (col < 1024) {
          int c = col - 512, h = c >> 6, d = c & 63;
          int bh2 = b * 8 + h;
          int t = n >> 4, l15 = n & 15;
          int half = d >> 5, qd = (d >> 3) & 3, e = d & 7;
          kfrag[(size_t)bh2 * 65536 + t * 1024 + half * 512 + (qd * 16 + l15) * 8 + e] = f2bf(v);
        } else if (col < 1536) {
          int c = col - 1024, h = c >> 6, d = c & 63;
          int bh2 = b * 8 + h;
          int t64 = n >> 6, ck = (n >> 5) & 1, qd = (n >> 3) & 3, e = n & 7;
          int dt = d >> 4, l15 = d & 15;
          vfrag[(size_t)bh2 * 65536 + t64 * 4096 + dt * 1024 + ck * 512 + (qd * 16 + l15) * 8 + e] = f2bf(v);
        } else {
          int c = col - 1536;
          float g = 1.0f / (1.0f + __expf(-(v + bg[c])));
          gb[row * 512 + c] = f2bf(g);
        }
      }
}

// ------- fused attention: 32 q-rows/block, grid (32,32)=1024 -> 4 blocks/CU --
// (unchanged from round 5)
__global__ __launch_bounds__(256, 4) void attn_k(
    const u16* __restrict__ qb, const u16* __restrict__ kfrag, const u16* __restrict__ vfrag,
    const float* __restrict__ bias, const u16* __restrict__ gb, u16* __restrict__ ogb) {
  __shared__ __attribute__((aligned(16))) u16 Kt[2][4096];   // 2 x 8 KB frag-order keys
  __shared__ __attribute__((aligned(16))) u16 Vt[2][4096];   // 2 x 8 KB frag-order values
  __shared__ __attribute__((aligned(16))) u16 Ps[4 * 16 * 40];
  const int tid = threadIdx.x;
  const int wave = tid >> 6, lane = tid & 63;
  const int lane15 = lane & 15, quad = lane >> 4;
  const int bh = blockIdx.x;
  const int q0 = blockIdx.y * 32;
  const int qw = (wave & 1) * 16;   // wave's q-sub-tile
  const int kh = wave >> 1;         // wave's 32-key half of each 64-key tile

  bf16x8 qf0, qf1;
  {
    const u16* qrow = qb + ((size_t)(bh * 1024 + q0 + qw + lane15)) * 64 + quad * 8;
    qf0 = *(const bf16x8*)(qrow);
    qf1 = *(const bf16x8*)(qrow + 32);
  }
  bf16x8 ones;
#pragma unroll
  for (int e = 0; e < 8; ++e) ones[e] = __builtin_bit_cast(__bf16, (u16)0x3F80);

  floatx4 oacc[4] = {};
  floatx4 lacc = {};

  u16* Pw = Ps + wave * (16 * 40);
  const u16* kp = kfrag + (size_t)bh * 65536;
  const u16* vp = vfrag + (size_t)bh * 65536;
  const float* bbase = bias + ((size_t)(bh * 1024 + q0 + qw + quad * 4)) * 1024 + kh * 32 + lane15;

  auto stage = [&](int kt, int bufi) {
    const u16* kS = kp + kt * 4096;
    const u16* vS = vp + kt * 4096;
#pragma unroll
    for (int c = 0; c < 2; ++c) {
      int ch = wave * 2 + c;
      __builtin_amdgcn_global_load_lds((glob_u8*)(kS + ch * 512 + lane * 8),
                                       (lds_u8*)(&Kt[bufi][ch * 512]), 16, 0, 0);
      __builtin_amdgcn_global_load_lds((glob_u8*)(vS + ch * 512 + lane * 8),
                                       (lds_u8*)(&Vt[bufi][ch * 512]), 16, 0, 0);
    }
  };

  stage(0, 0);
  __syncthreads();
  int cur = 0;
#pragma unroll 1
  for (int kt = 0; kt < 16; ++kt) {
    if (kt < 15) stage(kt + 1, cur ^ 1);
    float bv[4][2];
#pragma unroll
    for (int r = 0; r < 4; ++r)
#pragma unroll
      for (int j = 0; j < 2; ++j)
        bv[r][j] = bbase[r * 1024 + kt * 64 + j * 16];
    const u16* Ktc = Kt[cur];
    const u16* Vtc = Vt[cur];
    floatx4 s[2];
#pragma unroll
    for (int j = 0; j < 2; ++j) {
      const u16* kb = Ktc + (kh * 2 + j) * 1024 + lane * 8;
      bf16x8 kf0 = *(const bf16x8*)(kb);
      bf16x8 kf1 = *(const bf16x8*)(kb + 512);
      floatx4 z = {};
      z = MFMA(qf0, kf0, z);
      s[j] = MFMA(qf1, kf1, z);
    }
#pragma unroll
    for (int j = 0; j < 2; ++j)
#pragma unroll
      for (int r = 0; r < 4; ++r)
        s[j][r] = __expf(s[j][r] + bv[r][j] - 8.0f);
#pragma unroll
    for (int j = 0; j < 2; ++j)
#pragma unroll
      for (int r = 0; r < 4; ++r)
        Pw[(quad * 4 + r) * 40 + j * 16 + lane15] = f2bf(s[j][r]);
    bf16x8 pf = *(const bf16x8*)(Pw + lane15 * 40 + quad * 8);

    lacc = MFMA(pf, ones, lacc);
#pragma unroll
    for (int dt = 0; dt < 4; ++dt) {
      bf16x8 vf = *(const bf16x8*)(Vtc + dt * 1024 + kh * 512 + lane * 8);
      oacc[dt] = MFMA(pf, vf, oacc[dt]);
    }
    __syncthreads();
    cur ^= 1;
  }

  float* red = (float*)Kt;
  if (wave >= 2) {
    float* r0 = red + (wave - 2) * 1280 + lane * 20;
#pragma unroll
    for (int dt = 0; dt < 4; ++dt)
#pragma unroll
      for (int r = 0; r < 4; ++r) r0[dt * 4 + r] = oacc[dt][r];
#pragma unroll
    for (int r = 0; r < 4; ++r) r0[16 + r] = lacc[r];
  }
  __syncthreads();
  if (wave < 2) {
    const float* r0 = red + wave * 1280 + lane * 20;
#pragma unroll
    for (int dt = 0; dt < 4; ++dt)
#pragma unroll
      for (int r = 0; r < 4; ++r) oacc[dt][r] += r0[dt * 4 + r];
#pragma unroll
    for (int r = 0; r < 4; ++r) lacc[r] += r0[16 + r];

    const int b = bh >> 3, h = bh & 7;
#pragma unroll
    for (int r = 0; r < 4; ++r) {
      int q = q0 + wave * 16 + quad * 4 + r;
      float inv = 1.0f / lacc[r];
      size_t base = ((size_t)(b * 1024 + q)) * 512 + h * 64;
#pragma unroll
      for (int dt = 0; dt < 4; ++dt) {
        size_t gi = base + dt * 16 + lane15;
        ogb[gi] = f2bf(oacc[dt][r] * inv * bf2f(gb[gi]));
      }
    }
  }
}

// ------- GEMM2: 64x64 tiles (proven config), full K=512, fused +bo -----------
__global__ __launch_bounds__(256, 4) void gemm_out_k(
    const u16* __restrict__ og, const u16* __restrict__ WoT,
    const float* __restrict__ bo, float* __restrict__ out) {
  __shared__ __attribute__((aligned(16))) u16 As[64 * 40];
  __shared__ __attribute__((aligned(16))) u16 Bs[64 * 40];
  const int tid = threadIdx.x;
  const int wave = tid >> 6, lane = tid & 63;
  const int lane15 = lane & 15, quad = lane >> 4;
  const int rm0 = blockIdx.x * 64;
  const int cn0 = blockIdx.y * 64;
  const int wm = (wave & 1) * 32, wn = (wave >> 1) * 32;
  const int rowA = tid >> 2, segA = (tid & 3) * 8;
  floatx4 acc[2][2] = {};
  uint4 a0 = *(const uint4*)(og + (rm0 + rowA) * 512 + segA);
  uint4 b0 = *(const uint4*)(WoT + (cn0 + rowA) * 512 + segA);
#pragma unroll 1
  for (int k0 = 0; k0 < 512; k0 += 32) {
    __syncthreads();
    *(uint4*)(As + rowA * 40 + segA) = a0;
    *(uint4*)(Bs + rowA * 40 + segA) = b0;
    __syncthreads();
    if (k0 < 480) {
      a0 = *(const uint4*)(og + (rm0 + rowA) * 512 + k0 + 32 + segA);
      b0 = *(const uint4*)(WoT + (cn0 + rowA) * 512 + k0 + 32 + segA);
    }
    bf16x8 af[2], bfr[2];
#pragma unroll
    for (int mt = 0; mt < 2; ++mt) af[mt] = *(const bf16x8*)(As + (wm + mt * 16 + lane15) * 40 + quad * 8);
#pragma unroll
    for (int nt = 0; nt < 2; ++nt) bfr[nt] = *(const bf16x8*)(Bs + (wn + nt * 16 + lane15) * 40 + quad * 8);
#pragma unroll
    for (int mt = 0; mt < 2; ++mt)
#pragma unroll
      for (int nt = 0; nt < 2; ++nt)
        acc[mt][nt] = MFMA(af[mt], bfr[nt], acc[mt][nt]);
  }
#pragma unroll
  for (int nt = 0; nt < 2; ++nt) {
    int col = cn0 + wn + nt * 16 + lane15;
    float bv = bo[col];
#pragma unroll
    for (int mt = 0; mt < 2; ++mt)
#pragma unroll
      for (int r = 0; r < 4; ++r) {
        int row = rm0 + wm + mt * 16 + quad * 4 + r;
        out[(size_t)row * 256 + col] = acc[mt][nt][r] + bv;
      }
  }
}

extern "C" void kernel_launch(void* const* d_in, const int* in_sizes, int n_in,
                              void* d_out, int out_size, void* d_ws, size_t ws_size,
                              hipStream_t stream) {
  const float* x = (const float*)d_in[0];
  const float* bias = (const float*)d_in[1];
  const float* Wq = (const float*)d_in[2];
  const float* Wkv = (const float*)d_in[3];
  const float* Wo = (const float*)d_in[4];
  const float* bo = (const float*)d_in[5];
  const float* Wg = (const float*)d_in[6];
  const float* bg = (const float*)d_in[7];
  float* out = (float*)d_out;
  char* ws = (char*)d_ws;
  u16* xA    = (u16*)(ws);                 // 2 MB (frag-tile order)
  u16* WB    = (u16*)(ws + 2097152);       // 1 MB (frag-tile order)
  u16* WoT   = (u16*)(ws + 3145728);       // 256 KB
  u16* qb    = (u16*)(ws + 3407872);       // 4 MB
  u16* kfrag = (u16*)(ws + 7602176);       // 4 MB
  u16* vfrag = (u16*)(ws + 11796480);      // 4 MB
  u16* gb    = (u16*)(ws + 15990784);      // 4 MB
  u16* ogb   = (u16*)(ws + 20185088);      // 4 MB

  convert_k<<<1280, 256, 0, stream>>>(x, Wq, Wkv, Wg, Wo, xA, WB, WoT);
  dim3 g1(32, 32);
  gemm_qkvg<<<g1, 256, 0, stream>>>(xA, WB, bg, qb, kfrag, vfrag, gb);
  dim3 g2(32, 32);
  attn_k<<<g2, 256, 0, stream>>>(qb, kfrag, vfrag, bias, gb, ogb);
  dim3 g3(64, 4);
  gemm_out_k<<<g3, 256, 0, stream>>>(ogb, WoT, bo, out);
}